// Round 1
// 1084.761 us; speedup vs baseline: 1.0115x; 1.0115x over previous
//
#include <hip/hip_runtime.h>
#include <math.h>

typedef __bf16 bf16x8 __attribute__((ext_vector_type(8)));
typedef float f32x4 __attribute__((ext_vector_type(4)));

#define BM 256
#define BN 256
#define BK 64

__device__ __forceinline__ unsigned short f2bf(float f) {
    union { float f; unsigned u; } x; x.f = f;
    unsigned r = x.u + 0x7FFFu + ((x.u >> 16) & 1u);
    return (unsigned short)(r >> 16);
}

// erf-GELU via Abramowitz-Stegun 7.1.26 (|err| <= 1.5e-7), branchless.
__device__ __forceinline__ float fast_gelu(float h) {
    const float z  = __builtin_fabsf(h) * 0.70710678118654752f;
    const float t  = __builtin_amdgcn_rcpf(__builtin_fmaf(0.3275911f, z, 1.0f));
    float p = 1.061405429f;
    p = __builtin_fmaf(p, t, -1.453152027f);
    p = __builtin_fmaf(p, t,  1.421413741f);
    p = __builtin_fmaf(p, t, -0.284496736f);
    p = __builtin_fmaf(p, t,  0.254829592f);
    const float ez = __builtin_amdgcn_exp2f(-z * z * 1.4426950408889634f);
    float erfz = __builtin_fmaf(-p * t, ez, 1.0f);
    erfz = (h < 0.0f) ? -erfz : erfz;
    return 0.5f * h * (1.0f + erfz);
}

#define GLOAD_LDS16(GP, LP)                                                      \
    __builtin_amdgcn_global_load_lds(                                            \
        (const __attribute__((address_space(1))) unsigned int*)(GP),             \
        (__attribute__((address_space(3))) unsigned int*)(LP), 16, 0, 0)

// ---- 256x256 tile, 4-quadrant-phase K-loop with counted vmcnt (T2+T3+T4+T5).
// LDS tiles XOR-swizzled: physical 16B-chunk pc of row r holds global chunk
// pc ^ (r&7)  (applied via the staging lane's pre-swizzled global address;
// global_load_lds LDS dest is linear base + lane*16).
//
// Stage order per iter t (into slot t^1): ph0: A-h0(t+1), ph1: B-h0(t+1),
// ph2: B-h1(t+1), ph3: A-h1(t+1).  Reads of iter t+1: ph0 needs A-h0,B-h0
// (confirmed by vmcnt(4) at end of iter-t ph3), ph1 needs B-h1 (end-ph0 wait),
// ph2 needs A-h1 (end-ph1 wait), ph3 re-reads B-h0 (long confirmed).
// All confirm-waits precede a barrier -> cross-wave visible.  Waits are
// vmcnt(4), never 0: 2 half-tiles (4 loads/thread) stay in flight.

#define STAGE_A(sl, h, kto) do {                                                      \
    GLOAD_LDS16(Ag + (size_t)((h) * 128 + 0) * K + (kto), &As[sl][((h) * 128 + stRow + 0) * BK]); \
    GLOAD_LDS16(Ag + (size_t)((h) * 128 + 8) * K + (kto), &As[sl][((h) * 128 + stRow + 8) * BK]); \
} while (0)

#define STAGE_B(sl, h, kto) do {                                                      \
    GLOAD_LDS16(Bg + (size_t)((h) * 128 + 0) * K + (kto), &Bs[sl][((h) * 128 + stRow + 0) * BK]); \
    GLOAD_LDS16(Bg + (size_t)((h) * 128 + 8) * K + (kto), &Bs[sl][((h) * 128 + stRow + 8) * BK]); \
} while (0)

#define LDA(sl, rh) do {                                                              \
    const unsigned short* _pa = &As[sl][((rh) * 128 + wm * 64 + lr) * BK];            \
    _Pragma("unroll") for (int _i = 0; _i < 4; ++_i) {                                \
        af[_i][0] = *(const bf16x8*)&_pa[_i * 16 * BK + pc0];                         \
        af[_i][1] = *(const bf16x8*)&_pa[_i * 16 * BK + pc1];                         \
    }                                                                                 \
} while (0)

#define LDB(sl, ch) do {                                                              \
    const unsigned short* _pb = &Bs[sl][((ch) * 128 + wn * 32 + lr) * BK];            \
    _Pragma("unroll") for (int _j = 0; _j < 2; ++_j) {                                \
        bfr[_j][0] = *(const bf16x8*)&_pb[_j * 16 * BK + pc0];                        \
        bfr[_j][1] = *(const bf16x8*)&_pb[_j * 16 * BK + pc1];                        \
    }                                                                                 \
} while (0)

#define MM(rh, ch) do {                                                               \
    _Pragma("unroll") for (int _i = 0; _i < 4; ++_i)                                  \
    _Pragma("unroll") for (int _j = 0; _j < 2; ++_j) {                                \
        acc[(rh) * 4 + _i][(ch) * 2 + _j] = __builtin_amdgcn_mfma_f32_16x16x32_bf16(  \
            af[_i][0], bfr[_j][0], acc[(rh) * 4 + _i][(ch) * 2 + _j], 0, 0, 0);       \
        acc[(rh) * 4 + _i][(ch) * 2 + _j] = __builtin_amdgcn_mfma_f32_16x16x32_bf16(  \
            af[_i][1], bfr[_j][1], acc[(rh) * 4 + _i][(ch) * 2 + _j], 0, 0, 0);       \
    }                                                                                 \
} while (0)

#define MIDBAR() do {                                                                 \
    __builtin_amdgcn_s_barrier();                                                     \
    asm volatile("s_waitcnt lgkmcnt(0)" ::: "memory");                                \
    __builtin_amdgcn_sched_barrier(0);                                                \
} while (0)

#define ENDBAR_W() do {                                                               \
    asm volatile("s_waitcnt vmcnt(4)" ::: "memory");                                  \
    __builtin_amdgcn_s_barrier();                                                     \
} while (0)

#define ENDBAR_N() do {                                                               \
    asm volatile("" ::: "memory");                                                    \
    __builtin_amdgcn_s_barrier();                                                     \
} while (0)

// C = A * Bt^T (+bias fp32, optional erf-GELU).
// A: [localRows][K] bf16 row-major.  Bt: [E][N][K] bf16 (K contiguous).
template <bool GELU, bool OUT_F32>
__global__ __launch_bounds__(512, 2) void gemm_bt(
    const unsigned short* __restrict__ A,
    const unsigned short* __restrict__ Bt,
    const float* __restrict__ bias,
    void* __restrict__ Cv,
    int N, int K, int groupStart, int eStride, int groupPitch)
{
    __shared__ __attribute__((aligned(16))) unsigned short As[2][BM * BK];
    __shared__ __attribute__((aligned(16))) unsigned short Bs[2][BN * BK];

    const int tid  = threadIdx.x;
    const int lane = tid & 63;
    const int w    = tid >> 6;        // 0..7
    const int wm   = w & 1;           // owns 64-row stripe inside each 128-row half
    const int wn   = w >> 1;          // owns 32-col stripe inside each 128-col half

    const int rowBase = blockIdx.y * BM;
    const int colBase = blockIdx.x * BN;
    const int e = (groupStart + (int)(blockIdx.y >> 3) * eStride) & 7;

    // Staging: wave w covers rows [h*128 + w*16, +16) per half, 2 loads/thread.
    const int sRow   = w * 16 + (lane >> 3);
    const int sChunk = ((lane & 7) ^ (lane >> 3)) * 8;   // pre-swizzled, in shorts
    const unsigned short* Ag = A + (size_t)(rowBase + sRow) * K + sChunk;
    const unsigned short* Bg = Bt + (size_t)e * N * K
                              + (size_t)(colBase + sRow) * K + sChunk;
    const int stRow = w * 16;

    const int lr  = lane & 15;
    const int q   = lane >> 4;
    const int pc0 = ((0 + q) ^ (lr & 7)) * 8;   // un-swizzled chunk, k-slice 0
    const int pc1 = ((4 + q) ^ (lr & 7)) * 8;   // k-slice 1

    f32x4 acc[8][4];
    #pragma unroll
    for (int i = 0; i < 8; ++i)
        #pragma unroll
        for (int j = 0; j < 4; ++j)
            acc[i][j] = (f32x4){0.f, 0.f, 0.f, 0.f};

    bf16x8 af[4][2];
    bf16x8 bfr[2][2];

    const int NT = K / BK;

    // Prologue: tile 0, stage order A0,B0,B1,A1; confirm A0,B0; leave B1,A1 in flight.
    STAGE_A(0, 0, 0);
    STAGE_B(0, 0, 0);
    STAGE_B(0, 1, 0);
    STAGE_A(0, 1, 0);
    asm volatile("s_waitcnt vmcnt(4)" ::: "memory");
    __builtin_amdgcn_s_barrier();

    for (int t = 0; t < NT; ++t) {
        const int sl  = t & 1;
        const int ns  = sl ^ 1;
        const int ktn = (t + 1 == NT) ? 0 : (t + 1) * BK;   // wrap: harmless reload

        // phase 0: quadrant (rh=0, ch=0)
        LDA(sl, 0); LDB(sl, 0);
        STAGE_A(ns, 0, ktn);
        MIDBAR();
        __builtin_amdgcn_s_setprio(1); MM(0, 0); __builtin_amdgcn_s_setprio(0);
        ENDBAR_W();                                   // confirms B-h1(t)

        // phase 1: (rh=0, ch=1)  (af reused)
        LDB(sl, 1);
        STAGE_B(ns, 0, ktn);
        MIDBAR();
        __builtin_amdgcn_s_setprio(1); MM(0, 1); __builtin_amdgcn_s_setprio(0);
        ENDBAR_W();                                   // confirms A-h1(t)

        // phase 2: (rh=1, ch=1)  (bfr reused)
        LDA(sl, 1);
        STAGE_B(ns, 1, ktn);
        MIDBAR();
        __builtin_amdgcn_s_setprio(1); MM(1, 1); __builtin_amdgcn_s_setprio(0);
        ENDBAR_N();                                   // nothing to confirm

        // phase 3: (rh=1, ch=0)  (af reused, B-h0 re-read)
        LDB(sl, 0);
        STAGE_A(ns, 1, ktn);
        MIDBAR();
        __builtin_amdgcn_s_setprio(1); MM(1, 0); __builtin_amdgcn_s_setprio(0);
        ENDBAR_W();                                   // confirms A-h0,B-h0(t+1)
    }
    asm volatile("s_waitcnt vmcnt(0)" ::: "memory");  // drain tail prefetch before endpgm

    // Epilogue.  C/D layout: col = lane&15, row = (lane>>4)*4 + reg   [m89]
    const float* be = bias + (size_t)e * N;
    float bj[2][2];
    #pragma unroll
    for (int ch = 0; ch < 2; ++ch)
        #pragma unroll
        for (int j = 0; j < 2; ++j)
            bj[ch][j] = be[colBase + ch * 128 + wn * 32 + j * 16 + lr];

    #pragma unroll
    for (int rh = 0; rh < 2; ++rh)
    #pragma unroll
    for (int i = 0; i < 4; ++i)
    #pragma unroll
    for (int r = 0; r < 4; ++r) {
        const int rowLocal = rowBase + rh * 128 + wm * 64 + i * 16 + q * 4 + r;
        const int rowG = (rowLocal >> 11) * groupPitch + (rowLocal & 2047);
        #pragma unroll
        for (int ch = 0; ch < 2; ++ch)
        #pragma unroll
        for (int j = 0; j < 2; ++j) {
            const int col = colBase + ch * 128 + wn * 32 + j * 16 + lr;
            float v = acc[rh * 4 + i][ch * 2 + j][r] + bj[ch][j];
            if (GELU) v = fast_gelu(v);
            if (OUT_F32)
                ((float*)Cv)[(size_t)rowG * N + col] = v;
            else
                ((unsigned short*)Cv)[(size_t)rowG * N + col] = f2bf(v);
        }
    }
}

// W fp32 [R][C] (expert = blockIdx.z) -> Wt bf16 [C][R]
__global__ __launch_bounds__(256) void transpose_cvt(
    const float* __restrict__ W, unsigned short* __restrict__ Wt,
    int R, int C)
{
    __shared__ unsigned short t64[64][68];
    const int t = threadIdx.x;
    const int r0 = blockIdx.y * 64, c0 = blockIdx.x * 64;
    const float* Wp = W + (size_t)blockIdx.z * R * C;
    unsigned short* Wtp = Wt + (size_t)blockIdx.z * R * C;

    #pragma unroll
    for (int p = 0; p < 4; ++p) {
        const int row = p * 16 + (t >> 4);
        const int c4  = (t & 15) * 4;
        float4 v = *(const float4*)&Wp[(size_t)(r0 + row) * C + c0 + c4];
        t64[row][c4 + 0] = f2bf(v.x);
        t64[row][c4 + 1] = f2bf(v.y);
        t64[row][c4 + 2] = f2bf(v.z);
        t64[row][c4 + 3] = f2bf(v.w);
    }
    __syncthreads();
    #pragma unroll
    for (int p = 0; p < 4; ++p) {
        const int oc = p * 16 + (t >> 4);
        const int r4 = (t & 15) * 4;
        ushort4 o;
        o.x = t64[r4 + 0][oc];
        o.y = t64[r4 + 1][oc];
        o.z = t64[r4 + 2][oc];
        o.w = t64[r4 + 3][oc];
        *(ushort4*)&Wtp[(size_t)(c0 + oc) * R + r0 + r4] = o;
    }
}

__global__ __launch_bounds__(256) void cvt_f32_bf16(
    const float* __restrict__ in, unsigned short* __restrict__ out, long long n)
{
    long long i = ((long long)blockIdx.x * 256 + threadIdx.x) * 4;
    if (i < n) {
        float4 v = *(const float4*)&in[i];
        ushort4 o;
        o.x = f2bf(v.x); o.y = f2bf(v.y); o.z = f2bf(v.z); o.w = f2bf(v.w);
        *(ushort4*)&out[i] = o;
    }
}

extern "C" void kernel_launch(void* const* d_in, const int* in_sizes, int n_in,
                              void* d_out, int out_size, void* d_ws, size_t ws_size,
                              hipStream_t stream) {
    const float* x  = (const float*)d_in[0];
    const float* w1 = (const float*)d_in[1];
    const float* b1 = (const float*)d_in[2];
    const float* w2 = (const float*)d_in[3];
    const float* b2 = (const float*)d_in[4];
    float* out = (float*)d_out;
    unsigned short* ws = (unsigned short*)d_ws;

    const int E = 8, D = 1024, F = 4096, Bdim = 2, Cap = 2048;
    const int T = E * Cap;                       // 16384
    const size_t xbE = (size_t)Bdim * T * D;     // 33,554,432
    const size_t wE  = (size_t)E * D * F;        // 33,554,432
    const size_t gE  = (size_t)Cap * F;          // 8,388,608 (H elems per group)

    dim3 blk(256);
    dim3 gblk(512);
    const size_t fullBytes = (xbE + 2 * wE + gE) * 2;   // 218,103,808

    if (ws_size >= fullBytes) {
        // FULL path: everything converted once, groups batched.
        unsigned short* xb  = ws;
        unsigned short* w1t = ws + xbE;
        unsigned short* w2t = ws + xbE + wE;
        unsigned short* H   = ws + xbE + 2 * wE;
        int gpc = (int)((ws_size / 2 - (xbE + 2 * wE)) / gE);
        if (gpc > 16) gpc = 16;
        if (gpc < 1)  gpc = 1;

        cvt_f32_bf16<<<(unsigned)((xbE / 4 + 255) / 256), blk, 0, stream>>>(x, xb, (long long)xbE);
        transpose_cvt<<<dim3(F / 64, D / 64, E), blk, 0, stream>>>(w1, w1t, D, F);
        transpose_cvt<<<dim3(D / 64, F / 64, E), blk, 0, stream>>>(w2, w2t, F, D);

        for (int g0 = 0; g0 < Bdim * E; g0 += gpc) {
            const int ng = (g0 + gpc <= Bdim * E) ? gpc : (Bdim * E - g0);
            gemm_bt<true, false><<<dim3(F / BN, ng * 8), gblk, 0, stream>>>(
                xb + (size_t)g0 * Cap * D, w1t, b1, H, F, D, g0, 1, 2048);
            gemm_bt<false, true><<<dim3(D / BN, ng * 8), gblk, 0, stream>>>(
                H, w2t, b2, out + (size_t)g0 * Cap * D, D, F, g0, 1, 2048);
        }
    } else {
        // LEAN path: per-expert, both b-groups batched.  ~59 MB of ws.
        unsigned short* w1t = ws;                               // F*D
        unsigned short* w2t = w1t + (size_t)F * D;              // D*F
        unsigned short* xb  = w2t + (size_t)D * F;              // 2*Cap*D
        unsigned short* H   = xb + 2 * (size_t)Cap * D;         // 2*Cap*F

        for (int e = 0; e < E; ++e) {
            transpose_cvt<<<dim3(F / 64, D / 64, 1), blk, 0, stream>>>(
                w1 + (size_t)e * D * F, w1t, D, F);
            transpose_cvt<<<dim3(D / 64, F / 64, 1), blk, 0, stream>>>(
                w2 + (size_t)e * F * D, w2t, F, D);
            for (int b = 0; b < Bdim; ++b)
                cvt_f32_bf16<<<(unsigned)(((size_t)Cap * D / 4 + 255) / 256), blk, 0, stream>>>(
                    x + ((size_t)b * T + (size_t)e * Cap) * D,
                    xb + (size_t)b * Cap * D, (long long)Cap * D);
            gemm_bt<true, false><<<dim3(F / BN, 16), gblk, 0, stream>>>(
                xb, w1t, b1, H, F, D, e, 0, 2048);
            gemm_bt<false, true><<<dim3(D / BN, 16), gblk, 0, stream>>>(
                H, w2t, b2, out + (size_t)e * Cap * D, D, F, e, 0, T);
        }
    }
}

// Round 2
// 1036.735 us; speedup vs baseline: 1.0583x; 1.0463x over previous
//
#include <hip/hip_runtime.h>
#include <math.h>

typedef __bf16 bf16x8 __attribute__((ext_vector_type(8)));
typedef float f32x4 __attribute__((ext_vector_type(4)));

#define BM 256
#define BN 256
#define BK 64

__device__ __forceinline__ unsigned short f2bf(float f) {
    union { float f; unsigned u; } x; x.f = f;
    unsigned r = x.u + 0x7FFFu + ((x.u >> 16) & 1u);
    return (unsigned short)(r >> 16);
}

// erf-GELU via Abramowitz-Stegun 7.1.26 (|err| <= 1.5e-7), branchless.
__device__ __forceinline__ float fast_gelu(float h) {
    const float z  = __builtin_fabsf(h) * 0.70710678118654752f;
    const float t  = __builtin_amdgcn_rcpf(__builtin_fmaf(0.3275911f, z, 1.0f));
    float p = 1.061405429f;
    p = __builtin_fmaf(p, t, -1.453152027f);
    p = __builtin_fmaf(p, t,  1.421413741f);
    p = __builtin_fmaf(p, t, -0.284496736f);
    p = __builtin_fmaf(p, t,  0.254829592f);
    const float ez = __builtin_amdgcn_exp2f(-z * z * 1.4426950408889634f);
    float erfz = __builtin_fmaf(-p * t, ez, 1.0f);
    erfz = (h < 0.0f) ? -erfz : erfz;
    return 0.5f * h * (1.0f + erfz);
}

#define GLOAD_LDS16(GP, LP)                                                      \
    __builtin_amdgcn_global_load_lds(                                            \
        (const __attribute__((address_space(1))) unsigned int*)(GP),             \
        (__attribute__((address_space(3))) unsigned int*)(LP), 16, 0, 0)

// ---- m201-faithful 256x256 8-phase schedule (T2+T3+T4+T5) ----
// 2 K-tiles per outer iter: buf0 = even tile t, buf1 = odd tile t+1.
// Per tile, quadrant order q(0,0),q(0,1),q(1,1),q(1,0); af (A frags) loaded at
// q(0,0)/q(1,1), bfr (B frags) at every phase (B-h0 re-read at q(1,0)).
// Stage exactly ONE half-tile per phase:
//   ph1: Bh0(t+1)  ph2: Ah0(t+2)  ph3: Bh1(t+2)  ph4: Ah1(t+2)  [vmcnt(6)]
//   ph5: Bh0(t+2)  ph6: Ah0(t+3)  ph7: Bh1(t+3)  ph8: Ah1(t+3)  [vmcnt(6)]
// vmcnt(6) at ph4 retires exactly {Ah0,Bh1,Ah1,Bh0}(t+1) -> buf1 confirmed;
// at ph8 retires tile t+2 -> buf0 confirmed.  3 half-tiles stay in flight.
// Overwrite-safety: each stage targets a region whose last LDS read was in an
// earlier phase (>= one ENDBAR before the stage issue).  Last reads per tile:
// A-h0: q00 phase; B-h1: q01+q11; A-h1: q11; B-h0: q00+q10.
//
// LDS XOR-swizzle unchanged: physical 16B-chunk pc of row r holds global
// chunk pc ^ (r&7), applied via the staging lane's pre-swizzled global addr.

#define STAGE_A(sl, h, kto) do {                                                      \
    GLOAD_LDS16(Ag + (size_t)((h) * 128 + 0) * K + (kto), &As[sl][((h) * 128 + stRow + 0) * BK]); \
    GLOAD_LDS16(Ag + (size_t)((h) * 128 + 8) * K + (kto), &As[sl][((h) * 128 + stRow + 8) * BK]); \
} while (0)

#define STAGE_B(sl, h, kto) do {                                                      \
    GLOAD_LDS16(Bg + (size_t)((h) * 128 + 0) * K + (kto), &Bs[sl][((h) * 128 + stRow + 0) * BK]); \
    GLOAD_LDS16(Bg + (size_t)((h) * 128 + 8) * K + (kto), &Bs[sl][((h) * 128 + stRow + 8) * BK]); \
} while (0)

#define LDA(sl, rh) do {                                                              \
    const unsigned short* _pa = &As[sl][((rh) * 128 + wm * 64 + lr) * BK];            \
    _Pragma("unroll") for (int _i = 0; _i < 4; ++_i) {                                \
        af[_i][0] = *(const bf16x8*)&_pa[_i * 16 * BK + pc0];                         \
        af[_i][1] = *(const bf16x8*)&_pa[_i * 16 * BK + pc1];                         \
    }                                                                                 \
} while (0)

#define LDB(sl, ch) do {                                                              \
    const unsigned short* _pb = &Bs[sl][((ch) * 128 + wn * 32 + lr) * BK];            \
    _Pragma("unroll") for (int _j = 0; _j < 2; ++_j) {                                \
        bfr[_j][0] = *(const bf16x8*)&_pb[_j * 16 * BK + pc0];                        \
        bfr[_j][1] = *(const bf16x8*)&_pb[_j * 16 * BK + pc1];                        \
    }                                                                                 \
} while (0)

#define MM(rh, ch) do {                                                               \
    _Pragma("unroll") for (int _i = 0; _i < 4; ++_i)                                  \
    _Pragma("unroll") for (int _j = 0; _j < 2; ++_j) {                                \
        acc[(rh) * 4 + _i][(ch) * 2 + _j] = __builtin_amdgcn_mfma_f32_16x16x32_bf16(  \
            af[_i][0], bfr[_j][0], acc[(rh) * 4 + _i][(ch) * 2 + _j], 0, 0, 0);       \
        acc[(rh) * 4 + _i][(ch) * 2 + _j] = __builtin_amdgcn_mfma_f32_16x16x32_bf16(  \
            af[_i][1], bfr[_j][1], acc[(rh) * 4 + _i][(ch) * 2 + _j], 0, 0, 0);       \
    }                                                                                 \
} while (0)

// Phase sync pieces.  Bare lgkmcnt(0) (no clobber, no sched_barrier): the
// compiler's own per-operand waitcnts order ds_read->MFMA; we only pin the
// phase boundary with a zero-cost clobber AFTER each barrier so next-phase
// ds_reads cannot hoist above the barrier / vmcnt confirm.
#define MID() do {                                                                    \
    __builtin_amdgcn_s_barrier();                                                     \
    asm volatile("s_waitcnt lgkmcnt(0)");                                             \
} while (0)

#define ENDN() do {                                                                   \
    __builtin_amdgcn_s_barrier();                                                     \
    asm volatile("" ::: "memory");                                                    \
} while (0)

#define ENDW() do {                                                                   \
    asm volatile("s_waitcnt vmcnt(6)" ::: "memory");                                  \
    __builtin_amdgcn_s_barrier();                                                     \
    asm volatile("" ::: "memory");                                                    \
} while (0)

// C = A * Bt^T (+bias fp32, optional erf-GELU).
// A: [localRows][K] bf16 row-major.  Bt: [E][N][K] bf16 (K contiguous).
template <bool GELU, bool OUT_F32>
__global__ __launch_bounds__(512, 2) void gemm_bt(
    const unsigned short* __restrict__ A,
    const unsigned short* __restrict__ Bt,
    const float* __restrict__ bias,
    void* __restrict__ Cv,
    int N, int K, int groupStart, int eStride, int groupPitch)
{
    __shared__ __attribute__((aligned(16))) unsigned short As[2][BM * BK];
    __shared__ __attribute__((aligned(16))) unsigned short Bs[2][BN * BK];

    const int tid  = threadIdx.x;
    const int lane = tid & 63;
    const int w    = tid >> 6;        // 0..7
    const int wm   = w & 1;           // 64-row stripe inside each 128-row half
    const int wn   = w >> 1;          // 32-col stripe inside each 128-col half

    const int rowBase = blockIdx.y * BM;
    const int colBase = blockIdx.x * BN;
    const int e = (groupStart + (int)(blockIdx.y >> 3) * eStride) & 7;

    // Staging: wave w covers rows [h*128 + w*16, +16) per half, 2 loads/thread.
    const int sRow   = w * 16 + (lane >> 3);
    const int sChunk = ((lane & 7) ^ (lane >> 3)) * 8;   // pre-swizzled, in shorts
    const unsigned short* Ag = A + (size_t)(rowBase + sRow) * K + sChunk;
    const unsigned short* Bg = Bt + (size_t)e * N * K
                              + (size_t)(colBase + sRow) * K + sChunk;
    const int stRow = w * 16;

    const int lr  = lane & 15;
    const int q   = lane >> 4;
    const int pc0 = ((0 + q) ^ (lr & 7)) * 8;   // un-swizzled chunk, k-slice 0
    const int pc1 = ((4 + q) ^ (lr & 7)) * 8;   // k-slice 1

    f32x4 acc[8][4];
    #pragma unroll
    for (int i = 0; i < 8; ++i)
        #pragma unroll
        for (int j = 0; j < 4; ++j)
            acc[i][j] = (f32x4){0.f, 0.f, 0.f, 0.f};

    bf16x8 af[4][2];
    bf16x8 bfr[2][2];

    const int NT = K / BK;   // even (K = 1024 or 4096)

    // Prologue: buf0 = tile0 (4 halves), buf1 = tile1 (3 of 4 halves).
    // vmcnt(4) confirms Ah0(0),Bh0(0); vmcnt(6) confirms Ah1(0),Bh1(0).
    STAGE_A(0, 0, 0);
    STAGE_B(0, 0, 0);
    STAGE_A(0, 1, 0);
    STAGE_B(0, 1, 0);
    asm volatile("s_waitcnt vmcnt(4)" ::: "memory");
    STAGE_A(1, 0, BK);
    STAGE_B(1, 1, BK);
    STAGE_A(1, 1, BK);
    asm volatile("s_waitcnt vmcnt(6)" ::: "memory");
    __builtin_amdgcn_s_barrier();
    asm volatile("" ::: "memory");

    for (int t = 0; t < NT; t += 2) {
        const int k1 = (t + 1) * BK;
        const int ku = (t + 2 < NT) ? (t + 2) * BK : 0;   // wrap keeps ledger exact
        const int kv = (t + 3 < NT) ? (t + 3) * BK : 0;

        // ph1: buf0 q(0,0) | stage Bh0(t+1) -> buf1
        LDA(0, 0); LDB(0, 0);
        STAGE_B(1, 0, k1);
        asm volatile("s_waitcnt lgkmcnt(8)");     // 12 ds_reads issued this phase
        MID();
        __builtin_amdgcn_s_setprio(1); MM(0, 0); __builtin_amdgcn_s_setprio(0);
        ENDN();

        // ph2: buf0 q(0,1) | stage Ah0(t+2) -> buf0   [A-h0 last read ph1]
        LDB(0, 1);
        STAGE_A(0, 0, ku);
        MID();
        __builtin_amdgcn_s_setprio(1); MM(0, 1); __builtin_amdgcn_s_setprio(0);
        ENDN();

        // ph3: buf0 q(1,1) | stage Bh1(t+2) -> buf0   [B-h1 last read ph2... re-read here? no: bfr holds B-h1 from ph2]
        LDA(0, 1);
        STAGE_B(0, 1, ku);
        MID();
        __builtin_amdgcn_s_setprio(1); MM(1, 1); __builtin_amdgcn_s_setprio(0);
        ENDN();

        // ph4: buf0 q(1,0) | stage Ah1(t+2) -> buf0 [A-h1 read ph3] | confirm buf1
        LDB(0, 0);
        STAGE_A(0, 1, ku);
        MID();
        __builtin_amdgcn_s_setprio(1); MM(1, 0); __builtin_amdgcn_s_setprio(0);
        ENDW();                                   // vmcnt(6): tile t+1 confirmed

        // ph5: buf1 q(0,0) | stage Bh0(t+2) -> buf0  [B-h0 last read ph4]
        LDA(1, 0); LDB(1, 0);
        STAGE_B(0, 0, ku);
        asm volatile("s_waitcnt lgkmcnt(8)");
        MID();
        __builtin_amdgcn_s_setprio(1); MM(0, 0); __builtin_amdgcn_s_setprio(0);
        ENDN();

        // ph6: buf1 q(0,1) | stage Ah0(t+3) -> buf1  [A-h0 last read ph5]
        LDB(1, 1);
        STAGE_A(1, 0, kv);
        MID();
        __builtin_amdgcn_s_setprio(1); MM(0, 1); __builtin_amdgcn_s_setprio(0);
        ENDN();

        // ph7: buf1 q(1,1) | stage Bh1(t+3) -> buf1  [B-h1 last read ph6]
        LDA(1, 1);
        STAGE_B(1, 1, kv);
        MID();
        __builtin_amdgcn_s_setprio(1); MM(1, 1); __builtin_amdgcn_s_setprio(0);
        ENDN();

        // ph8: buf1 q(1,0) | stage Ah1(t+3) -> buf1 [A-h1 read ph7] | confirm buf0
        LDB(1, 0);
        STAGE_A(1, 1, kv);
        MID();
        __builtin_amdgcn_s_setprio(1); MM(1, 0); __builtin_amdgcn_s_setprio(0);
        ENDW();                                   // vmcnt(6): tile t+2 confirmed
    }
    asm volatile("s_waitcnt vmcnt(0)" ::: "memory");  // drain wrapped tail stages

    // Epilogue.  C/D layout: col = lane&15, row = (lane>>4)*4 + reg   [m89]
    const float* be = bias + (size_t)e * N;
    float bj[2][2];
    #pragma unroll
    for (int ch = 0; ch < 2; ++ch)
        #pragma unroll
        for (int j = 0; j < 2; ++j)
            bj[ch][j] = be[colBase + ch * 128 + wn * 32 + j * 16 + lr];

    #pragma unroll
    for (int rh = 0; rh < 2; ++rh)
    #pragma unroll
    for (int i = 0; i < 4; ++i)
    #pragma unroll
    for (int r = 0; r < 4; ++r) {
        const int rowLocal = rowBase + rh * 128 + wm * 64 + i * 16 + q * 4 + r;
        const int rowG = (rowLocal >> 11) * groupPitch + (rowLocal & 2047);
        #pragma unroll
        for (int ch = 0; ch < 2; ++ch)
        #pragma unroll
        for (int j = 0; j < 2; ++j) {
            const int col = colBase + ch * 128 + wn * 32 + j * 16 + lr;
            float v = acc[rh * 4 + i][ch * 2 + j][r] + bj[ch][j];
            if (GELU) v = fast_gelu(v);
            if (OUT_F32)
                ((float*)Cv)[(size_t)rowG * N + col] = v;
            else
                ((unsigned short*)Cv)[(size_t)rowG * N + col] = f2bf(v);
        }
    }
}

// W fp32 [R][C] (expert = blockIdx.z) -> Wt bf16 [C][R]
__global__ __launch_bounds__(256) void transpose_cvt(
    const float* __restrict__ W, unsigned short* __restrict__ Wt,
    int R, int C)
{
    __shared__ unsigned short t64[64][68];
    const int t = threadIdx.x;
    const int r0 = blockIdx.y * 64, c0 = blockIdx.x * 64;
    const float* Wp = W + (size_t)blockIdx.z * R * C;
    unsigned short* Wtp = Wt + (size_t)blockIdx.z * R * C;

    #pragma unroll
    for (int p = 0; p < 4; ++p) {
        const int row = p * 16 + (t >> 4);
        const int c4  = (t & 15) * 4;
        float4 v = *(const float4*)&Wp[(size_t)(r0 + row) * C + c0 + c4];
        t64[row][c4 + 0] = f2bf(v.x);
        t64[row][c4 + 1] = f2bf(v.y);
        t64[row][c4 + 2] = f2bf(v.z);
        t64[row][c4 + 3] = f2bf(v.w);
    }
    __syncthreads();
    #pragma unroll
    for (int p = 0; p < 4; ++p) {
        const int oc = p * 16 + (t >> 4);
        const int r4 = (t & 15) * 4;
        ushort4 o;
        o.x = t64[r4 + 0][oc];
        o.y = t64[r4 + 1][oc];
        o.z = t64[r4 + 2][oc];
        o.w = t64[r4 + 3][oc];
        *(ushort4*)&Wtp[(size_t)(c0 + oc) * R + r0 + r4] = o;
    }
}

__global__ __launch_bounds__(256) void cvt_f32_bf16(
    const float* __restrict__ in, unsigned short* __restrict__ out, long long n)
{
    long long i = ((long long)blockIdx.x * 256 + threadIdx.x) * 4;
    if (i < n) {
        float4 v = *(const float4*)&in[i];
        ushort4 o;
        o.x = f2bf(v.x); o.y = f2bf(v.y); o.z = f2bf(v.z); o.w = f2bf(v.w);
        *(ushort4*)&out[i] = o;
    }
}

extern "C" void kernel_launch(void* const* d_in, const int* in_sizes, int n_in,
                              void* d_out, int out_size, void* d_ws, size_t ws_size,
                              hipStream_t stream) {
    const float* x  = (const float*)d_in[0];
    const float* w1 = (const float*)d_in[1];
    const float* b1 = (const float*)d_in[2];
    const float* w2 = (const float*)d_in[3];
    const float* b2 = (const float*)d_in[4];
    float* out = (float*)d_out;
    unsigned short* ws = (unsigned short*)d_ws;

    const int E = 8, D = 1024, F = 4096, Bdim = 2, Cap = 2048;
    const int T = E * Cap;                       // 16384
    const size_t xbE = (size_t)Bdim * T * D;     // 33,554,432
    const size_t wE  = (size_t)E * D * F;        // 33,554,432
    const size_t gE  = (size_t)Cap * F;          // 8,388,608 (H elems per group)

    dim3 blk(256);
    dim3 gblk(512);
    const size_t fullBytes = (xbE + 2 * wE + gE) * 2;   // 218,103,808

    if (ws_size >= fullBytes) {
        // FULL path: everything converted once, groups batched.
        unsigned short* xb  = ws;
        unsigned short* w1t = ws + xbE;
        unsigned short* w2t = ws + xbE + wE;
        unsigned short* H   = ws + xbE + 2 * wE;
        int gpc = (int)((ws_size / 2 - (xbE + 2 * wE)) / gE);
        if (gpc > 16) gpc = 16;
        if (gpc < 1)  gpc = 1;

        cvt_f32_bf16<<<(unsigned)((xbE / 4 + 255) / 256), blk, 0, stream>>>(x, xb, (long long)xbE);
        transpose_cvt<<<dim3(F / 64, D / 64, E), blk, 0, stream>>>(w1, w1t, D, F);
        transpose_cvt<<<dim3(D / 64, F / 64, E), blk, 0, stream>>>(w2, w2t, F, D);

        for (int g0 = 0; g0 < Bdim * E; g0 += gpc) {
            const int ng = (g0 + gpc <= Bdim * E) ? gpc : (Bdim * E - g0);
            gemm_bt<true, false><<<dim3(F / BN, ng * 8), gblk, 0, stream>>>(
                xb + (size_t)g0 * Cap * D, w1t, b1, H, F, D, g0, 1, 2048);
            gemm_bt<false, true><<<dim3(D / BN, ng * 8), gblk, 0, stream>>>(
                H, w2t, b2, out + (size_t)g0 * Cap * D, D, F, g0, 1, 2048);
        }
    } else {
        // LEAN path: per-expert, both b-groups batched.  ~59 MB of ws.
        unsigned short* w1t = ws;                               // F*D
        unsigned short* w2t = w1t + (size_t)F * D;              // D*F
        unsigned short* xb  = w2t + (size_t)D * F;              // 2*Cap*D
        unsigned short* H   = xb + 2 * (size_t)Cap * D;         // 2*Cap*F

        for (int e = 0; e < E; ++e) {
            transpose_cvt<<<dim3(F / 64, D / 64, 1), blk, 0, stream>>>(
                w1 + (size_t)e * D * F, w1t, D, F);
            transpose_cvt<<<dim3(D / 64, F / 64, 1), blk, 0, stream>>>(
                w2 + (size_t)e * F * D, w2t, F, D);
            for (int b = 0; b < Bdim; ++b)
                cvt_f32_bf16<<<(unsigned)(((size_t)Cap * D / 4 + 255) / 256), blk, 0, stream>>>(
                    x + ((size_t)b * T + (size_t)e * Cap) * D,
                    xb + (size_t)b * Cap * D, (long long)Cap * D);
            gemm_bt<true, false><<<dim3(F / BN, 16), gblk, 0, stream>>>(
                xb, w1t, b1, H, F, D, e, 0, 2048);
            gemm_bt<false, true><<<dim3(D / BN, 16), gblk, 0, stream>>>(
                H, w2t, b2, out + (size_t)e * Cap * D, D, F, e, 0, T);
        }
    }
}